// Round 2
// baseline (603.925 us; speedup 1.0000x reference)
//
#include <hip/hip_runtime.h>

typedef __attribute__((ext_vector_type(8))) short bf16x8;
typedef __attribute__((ext_vector_type(4))) float f32x4;

static __device__ __forceinline__ unsigned short f2bf(float x) {
  union { float f; unsigned u; } c; c.f = x;
  unsigned r = c.u + 0x7fffu + ((c.u >> 16) & 1u);
  return (unsigned short)(r >> 16);
}

constexpr int SPLITS = 8;
constexpr int KCH = 8192 / SPLITS;   // 1024
constexpr int NSTEP = KCH / 32;      // 32

// ---------------- convert A fp32 -> bf16 ----------------
__global__ __launch_bounds__(256) void k_convert(const float* __restrict__ A,
                                                 unsigned short* __restrict__ Abf) {
  const long long n4 = (8192LL * 8192LL) / 4;
  long long i = (long long)blockIdx.x * blockDim.x + threadIdx.x;
  const long long stride = (long long)gridDim.x * blockDim.x;
  const float4* A4 = (const float4*)A;
  ushort4* O4 = (ushort4*)Abf;
  for (; i < n4; i += stride) {
    float4 v = A4[i];
    ushort4 o;
    o.x = f2bf(v.x); o.y = f2bf(v.y); o.z = f2bf(v.z); o.w = f2bf(v.w);
    O4[i] = o;
  }
}

// ---------------- g1t[n][m] = (X @ W1.T)^T, bf16 ----------------
__global__ __launch_bounds__(256) void k_first(const float* __restrict__ X,
                                               const float* __restrict__ W1,
                                               unsigned short* __restrict__ G1t) {
  __shared__ float Ws[32][32];
  const int t = threadIdx.x;
  for (int i = t; i < 1024; i += 256) Ws[i >> 5][i & 31] = W1[i];
  __syncthreads();
  const int m = blockIdx.x * 256 + t;
  float x[32];
  const float4* Xr = (const float4*)(X + (size_t)m * 32);
#pragma unroll
  for (int i = 0; i < 8; ++i) {
    float4 v = Xr[i];
    x[4 * i] = v.x; x[4 * i + 1] = v.y; x[4 * i + 2] = v.z; x[4 * i + 3] = v.w;
  }
#pragma unroll
  for (int n = 0; n < 32; ++n) {
    float acc = 0.f;
#pragma unroll
    for (int k = 0; k < 32; ++k) acc += x[k] * Ws[n][k];
    G1t[(size_t)n * 8192 + m] = f2bf(acc);
  }
}

// ---------------- big GEMM, register-direct streaming, no LDS/barriers -------
// Abf row-major [8192][8192] bf16, Gt transposed [D][8192] bf16 (L2-resident),
// P fp32 [SPLITS][8192][D]. 64-thread (1-wave) blocks, 32 rows/block.
// Fragments loaded straight to registers in MFMA layout: lane l = row l&15,
// k-slot l>>4 (16B contiguous). Double-buffered with NAMED registers so the
// compiler emits counted s_waitcnt vmcnt(6) — 12 loads stay in flight.
template <int D>
__global__ __launch_bounds__(64) void k_big(const unsigned short* __restrict__ Abf,
                                            const unsigned short* __restrict__ Gt,
                                            float* __restrict__ P) {
  constexpr int NT = D / 16;
  const int lane = threadIdx.x;
  const int lr = lane & 15, lk = lane >> 4;
  const int m0 = blockIdx.x * 32;
  const int kb = blockIdx.y * KCH;

  const unsigned short* a0 = Abf + (size_t)(m0 + lr) * 8192 + kb + lk * 8;
  const unsigned short* a1 = a0 + (size_t)16 * 8192;
  const unsigned short* g[NT];
#pragma unroll
  for (int i = 0; i < NT; ++i)
    g[i] = Gt + (size_t)(i * 16 + lr) * 8192 + kb + lk * 8;

  f32x4 acc[2][NT];
#pragma unroll
  for (int f = 0; f < 2; ++f)
#pragma unroll
    for (int i = 0; i < NT; ++i) acc[f][i] = (f32x4){0.f, 0.f, 0.f, 0.f};

  bf16x8 aA0, aA1, gA[NT];
  bf16x8 aB0, aB1, gB[NT];

#define LOAD(V0, V1, GV, S)                                   \
  do {                                                        \
    V0 = *(const bf16x8*)(a0 + (size_t)(S) * 32);             \
    V1 = *(const bf16x8*)(a1 + (size_t)(S) * 32);             \
    _Pragma("unroll") for (int i = 0; i < NT; ++i)            \
        GV[i] = *(const bf16x8*)(g[i] + (size_t)(S) * 32);    \
  } while (0)

#define COMP(V0, V1, GV)                                                         \
  do {                                                                           \
    _Pragma("unroll") for (int i = 0; i < NT; ++i) {                             \
      acc[0][i] = __builtin_amdgcn_mfma_f32_16x16x32_bf16(V0, GV[i], acc[0][i], 0, 0, 0); \
      acc[1][i] = __builtin_amdgcn_mfma_f32_16x16x32_bf16(V1, GV[i], acc[1][i], 0, 0, 0); \
    }                                                                            \
  } while (0)

  LOAD(aA0, aA1, gA, 0);
  LOAD(aB0, aB1, gB, 1);
  for (int s = 0; s < NSTEP - 2; s += 2) {
    COMP(aA0, aA1, gA);
    LOAD(aA0, aA1, gA, s + 2);
    COMP(aB0, aB1, gB);
    LOAD(aB0, aB1, gB, s + 3);
  }
  COMP(aA0, aA1, gA);
  COMP(aB0, aB1, gB);
#undef LOAD
#undef COMP

  // C/D layout: col = lane&15, row = (lane>>4)*4 + j  (verified in round 1)
  float* pw = P + ((size_t)blockIdx.y * 8192 + m0) * D;
#pragma unroll
  for (int f = 0; f < 2; ++f)
#pragma unroll
    for (int i = 0; i < NT; ++i)
#pragma unroll
      for (int j = 0; j < 4; ++j)
        pw[(size_t)(f * 16 + lk * 4 + j) * D + i * 16 + lr] = acc[f][i][j];
}

// ---------------- epilogue: h=relu(sum partials); Gt_next = (h @ W.T)^T bf16 ----
template <int D_IN, int D_OUT>
__global__ __launch_bounds__(256) void k_epi(const float* __restrict__ P,
                                             const float* __restrict__ W,
                                             unsigned short* __restrict__ Gtn) {
  __shared__ float h[64][D_IN + 1];
  __shared__ float Ws[D_OUT][D_IN];
  const int t = threadIdx.x;
  for (int i = t; i < D_OUT * D_IN; i += 256) Ws[i / D_IN][i % D_IN] = W[i];
  const int m0 = blockIdx.x * 64;
  for (int i = t; i < (64 * D_IN) / 4; i += 256) {
    int row = (i * 4) / D_IN;
    int c = (i * 4) % D_IN;
    const float* base = P + (size_t)(m0 + row) * D_IN + c;
    float4 s = *(const float4*)base;
#pragma unroll
    for (int ks = 1; ks < SPLITS; ++ks) {
      float4 v = *(const float4*)(base + (size_t)ks * 8192 * D_IN);
      s.x += v.x; s.y += v.y; s.z += v.z; s.w += v.w;
    }
    h[row][c] = fmaxf(s.x, 0.f);
    h[row][c + 1] = fmaxf(s.y, 0.f);
    h[row][c + 2] = fmaxf(s.z, 0.f);
    h[row][c + 3] = fmaxf(s.w, 0.f);
  }
  __syncthreads();
  const int ml = t & 63, q = t >> 6;
#pragma unroll
  for (int n2 = q * (D_OUT / 4); n2 < (q + 1) * (D_OUT / 4); ++n2) {
    float acc = 0.f;
#pragma unroll
    for (int k = 0; k < D_IN; ++k) acc += h[ml][k] * Ws[n2][k];
    Gtn[(size_t)n2 * 8192 + m0 + ml] = f2bf(acc);
  }
}

// ---------------- final: out = sum of partials (fp32) ----------------
__global__ __launch_bounds__(256) void k_final(const float* __restrict__ P,
                                               float* __restrict__ out) {
  const int i = blockIdx.x * 256 + threadIdx.x;  // 65536 float4s total
  const long long q = 8192LL * 32 / 4;
  const float4* P4 = (const float4*)P;
  float4 s = P4[i];
#pragma unroll
  for (int ks = 1; ks < SPLITS; ++ks) {
    float4 v = P4[i + (size_t)ks * q];
    s.x += v.x; s.y += v.y; s.z += v.z; s.w += v.w;
  }
  ((float4*)out)[i] = s;
}

extern "C" void kernel_launch(void* const* d_in, const int* in_sizes, int n_in,
                              void* d_out, int out_size, void* d_ws, size_t ws_size,
                              hipStream_t stream) {
  const float* A = (const float*)d_in[0];
  const float* X = (const float*)d_in[1];
  const float* W1 = (const float*)d_in[2];
  const float* W2 = (const float*)d_in[3];
  const float* W3 = (const float*)d_in[4];
  const float* W4 = (const float*)d_in[5];
  float* out = (float*)d_out;

  // ws layout
  const size_t ABF_OFF = 0;                          // 8192*8192*2 = 134217728
  const size_t GA_OFF = 134217728;                   // 64*8192*2 = 1048576
  const size_t GB_OFF = GA_OFF + 1048576;
  const size_t P_OFF = GB_OFF + 1048576;             // SPLITS*8192*64*4 = 16777216
  const size_t NEEDED = P_OFF + (size_t)SPLITS * 8192 * 64 * 4;
  if (ws_size < NEEDED) return;

  char* ws = (char*)d_ws;
  unsigned short* Abf = (unsigned short*)(ws + ABF_OFF);
  unsigned short* Ga = (unsigned short*)(ws + GA_OFF);
  unsigned short* Gb = (unsigned short*)(ws + GB_OFF);
  float* P = (float*)(ws + P_OFF);

  k_convert<<<2048, 256, 0, stream>>>(A, Abf);
  k_first<<<32, 256, 0, stream>>>(X, W1, Ga);                 // g1t [32][8192]
  k_big<32><<<dim3(256, SPLITS), 64, 0, stream>>>(Abf, Ga, P);
  k_epi<32, 64><<<128, 256, 0, stream>>>(P, W2, Gb);          // g2t [64][8192]
  k_big<64><<<dim3(256, SPLITS), 64, 0, stream>>>(Abf, Gb, P);
  k_epi<64, 64><<<128, 256, 0, stream>>>(P, W3, Ga);          // g3t [64][8192]
  k_big<64><<<dim3(256, SPLITS), 64, 0, stream>>>(Abf, Ga, P);
  k_epi<64, 32><<<128, 256, 0, stream>>>(P, W4, Gb);          // g4t [32][8192]
  k_big<32><<<dim3(256, SPLITS), 64, 0, stream>>>(Abf, Gb, P);
  k_final<<<256, 256, 0, stream>>>(P, out);
}